// Round 8
// baseline (754.434 us; speedup 1.0000x reference)
//
#include <hip/hip_runtime.h>

#define NN 100000
#define NE 1600000
#define DD 128
#define HH 16
#define CC 40
#define LL 3
#define GSTRIDE 2240   // per-layer Gram region: 8 copies x 272 + counter + pad

typedef int   vi4 __attribute__((ext_vector_type(4)));
typedef float vf4 __attribute__((ext_vector_type(4)));

__device__ __forceinline__ float4 f4fma(float s, float4 w, float4 a) {
    a.x = fmaf(s, w.x, a.x); a.y = fmaf(s, w.y, a.y);
    a.z = fmaf(s, w.z, a.z); a.w = fmaf(s, w.w, a.w);
    return a;
}

// bf16 helpers (RNE pack, shift unpack)
__device__ __forceinline__ unsigned short f2bf(float f) {
    unsigned u = __float_as_uint(f);
    unsigned r = u + 0x7fffu + ((u >> 16) & 1u);
    return (unsigned short)(r >> 16);
}
__device__ __forceinline__ unsigned pk2(float a, float b) {
    return (unsigned)f2bf(a) | ((unsigned)f2bf(b) << 16);
}
__device__ __forceinline__ float bflo(unsigned u) { return __uint_as_float(u << 16); }
__device__ __forceinline__ float bfhi(unsigned u) { return __uint_as_float(u & 0xffff0000u); }

// perm for [*][32]-float4 LDS arrays read at dw = p*4+dqi by 8 lanes p=0..7
__device__ __forceinline__ int permW2(int dw) {
    return (dw >> 2) | ((dw & 3) << 3);
}

// Edge-centric rowptr: rp[i] = first edge e with row[e] >= i (row sorted).
__global__ void build_rowptr(const int* __restrict__ row, int* __restrict__ rp) {
    int e = blockIdx.x * 256 + threadIdx.x;
    if (e >= NE) return;
    int r1 = row[e];
    int r0 = (e == 0) ? -1 : row[e - 1];
    for (int i = r0 + 1; i <= r1; i++) rp[i] = e;
    if (e == NE - 1) {
        for (int i = r1 + 1; i <= NN; i++) rp[i] = NE;
    }
}

__global__ void zero_buf(float* __restrict__ s, int n) {
    int i = blockIdx.x * 256 + threadIdx.x;
    if (i < n) s[i] = 0.f;
}

// ---- Y(bf16) = X @ W  (N x 128)@(128 x 16); thread-per-node ----
__launch_bounds__(256)
__global__ void gemm_dh_reg(const float* __restrict__ X, const float* __restrict__ W,
                            unsigned* __restrict__ Y) {
    __shared__ float4 Ws[DD * 4];
    int t = threadIdx.x;
    for (int i = t; i < DD * 4; i += 256) Ws[i] = ((const float4*)W)[i];
    __syncthreads();
    int n = blockIdx.x * 256 + t;
    if (n >= NN) return;
    const float4* X4 = (const float4*)(X + (size_t)n * DD);
    float4 y0 = {0,0,0,0}, y1 = {0,0,0,0}, y2 = {0,0,0,0}, y3 = {0,0,0,0};
    #pragma unroll 8
    for (int dc = 0; dc < 32; dc++) {
        float4 xv = X4[dc];
        float xs[4] = {xv.x, xv.y, xv.z, xv.w};
        #pragma unroll
        for (int j = 0; j < 4; j++) {
            int d = dc * 4 + j;
            float xj = xs[j];
            y0 = f4fma(xj, Ws[d * 4 + 0], y0);
            y1 = f4fma(xj, Ws[d * 4 + 1], y1);
            y2 = f4fma(xj, Ws[d * 4 + 2], y2);
            y3 = f4fma(xj, Ws[d * 4 + 3], y3);
        }
    }
    uint4 o0 = {pk2(y0.x, y0.y), pk2(y0.z, y0.w), pk2(y1.x, y1.y), pk2(y1.z, y1.w)};
    uint4 o1 = {pk2(y2.x, y2.y), pk2(y2.z, y2.w), pk2(y3.x, y3.y), pk2(y3.z, y3.w)};
    ((uint4*)Y)[(size_t)n * 2]     = o0;
    ((uint4*)Y)[(size_t)n * 2 + 1] = o1;
}

#define FMA_B(vv, g0, g1, g2, g3)                                                      \
    acc.x = fmaf(vv.x, bflo(g0.x), acc.x); acc.y = fmaf(vv.x, bfhi(g0.x), acc.y);      \
    acc.z = fmaf(vv.x, bflo(g0.y), acc.z); acc.w = fmaf(vv.x, bfhi(g0.y), acc.w);      \
    acc.x = fmaf(vv.y, bflo(g1.x), acc.x); acc.y = fmaf(vv.y, bfhi(g1.x), acc.y);      \
    acc.z = fmaf(vv.y, bflo(g1.y), acc.z); acc.w = fmaf(vv.y, bfhi(g1.y), acc.w);      \
    acc.x = fmaf(vv.z, bflo(g2.x), acc.x); acc.y = fmaf(vv.z, bfhi(g2.x), acc.y);      \
    acc.z = fmaf(vv.z, bflo(g2.y), acc.z); acc.w = fmaf(vv.z, bfhi(g2.y), acc.w);      \
    acc.x = fmaf(vv.w, bflo(g3.x), acc.x); acc.y = fmaf(vv.w, bfhi(g3.x), acc.y);      \
    acc.z = fmaf(vv.w, bflo(g3.y), acc.z); acc.w = fmaf(vv.w, bfhi(g3.y), acc.w);

// Aligned 4-edge batch load with range-zeroing: batch starts at jb (16B aligned,
// jb may dip below s and beyond e-1); out-of-range lanes get v=0 so the FMA is a
// no-op while col stays a valid gather address. NE % 4 == 0 keeps the last
// aligned vector load in-bounds. Plain loads: NT hints cost ~50-60us (R4/R6).
__device__ __forceinline__ void ldc(const int* __restrict__ col,
                                    const float* __restrict__ vals,
                                    int jb, int s, int e, vi4& c, vf4& v) {
    c = *(const vi4*)(col + jb);
    vf4 w = *(const vf4*)(vals + jb);
    int r = jb - s;
    unsigned deg = (unsigned)(e - s);
    v.x = ((unsigned)(r + 0) < deg) ? w.x : 0.f;
    v.y = ((unsigned)(r + 1) < deg) ? w.y : 0.f;
    v.z = ((unsigned)(r + 2) < deg) ? w.z : 0.f;
    v.w = ((unsigned)(r + 3) < deg) ? w.w : 0.f;
}

// ---- spmm over bf16 table; 4 lanes/node; fused Gram(+BN finalize) / classifier ----
// R2 structure exactly (best measured: 370us): 3-stage pipeline (load b+3,
// gather b+2, FMA b), natural node order, stale tails. GRAM additionally fuses
// bn_prep via last-block-done: threadfence -> atomic counter -> last block sums
// the 8 Gram copies (coherent atomic-reads) and computes SCSH in-kernel.
template <bool RELU, bool BIAS, bool OBF, bool GRAM, bool FINAL>
__launch_bounds__(256)
__global__ void spmm16(const int* __restrict__ rp, const int* __restrict__ col,
                       const float* __restrict__ vals, const unsigned* __restrict__ hin,
                       const float* __restrict__ bias, void* __restrict__ outv,
                       float* __restrict__ GS, const float* __restrict__ Wf,
                       const float* __restrict__ bf, float* __restrict__ outc,
                       const float* __restrict__ W2l, const float* __restrict__ b2l,
                       const float* __restrict__ gml, const float* __restrict__ btl,
                       float* __restrict__ SCSH) {
    __shared__ float2 Wc[FINAL ? HH * 20 : 1];
    __shared__ float2 Bc[FINAL ? 20 : 1];
    if (FINAL) {
        for (int i = threadIdx.x; i < HH * 20; i += 256) Wc[i] = ((const float2*)Wf)[i];
        if (threadIdx.x < 20) Bc[threadIdx.x] = ((const float2*)bf)[threadIdx.x];
    }
    int node = blockIdx.x * 64 + (threadIdx.x >> 2);
    int f = threadIdx.x & 3;
    bool valid = node < NN;
    if (!GRAM && !FINAL && !valid) return;
    float4 acc = {0, 0, 0, 0};
    if (valid) {
        int s = rp[node], e = rp[node + 1];
        const uint2* h2 = (const uint2*)hin;
        int deg = e - s;
        if (deg > 0) {
            int s0 = s & ~3;
            int B = (e - s0 + 3) >> 2;
            vi4 c2, c0, c1; vf4 v0, v1, v2;
            ldc(col, vals, s0, s, e, c0, v0);
            if (B > 1) ldc(col, vals, s0 + 4, s, e, c1, v1);
            else { c1 = c0; v1 = (vf4){0, 0, 0, 0}; }
            if (B > 2) ldc(col, vals, s0 + 8, s, e, c2, v2);
            else { c2 = c1; v2 = (vf4){0, 0, 0, 0}; }
            uint2 gA0 = h2[(size_t)c0.x * 4 + f], gA1 = h2[(size_t)c0.y * 4 + f];
            uint2 gA2 = h2[(size_t)c0.z * 4 + f], gA3 = h2[(size_t)c0.w * 4 + f];
            uint2 gB0 = h2[(size_t)c1.x * 4 + f], gB1 = h2[(size_t)c1.y * 4 + f];
            uint2 gB2 = h2[(size_t)c1.z * 4 + f], gB3 = h2[(size_t)c1.w * 4 + f];
            for (int b = 0; b < B; b++) {
                vi4 c3; vf4 v3;
                if (b + 3 < B) ldc(col, vals, s0 + ((b + 3) << 2), s, e, c3, v3);
                else { c3 = c2; v3 = (vf4){0, 0, 0, 0}; }
                uint2 gC0 = h2[(size_t)c2.x * 4 + f], gC1 = h2[(size_t)c2.y * 4 + f];
                uint2 gC2 = h2[(size_t)c2.z * 4 + f], gC3 = h2[(size_t)c2.w * 4 + f];
                FMA_B(v0, gA0, gA1, gA2, gA3)
                v0 = v1; v1 = v2; v2 = v3; c2 = c3;
                gA0 = gB0; gA1 = gB1; gA2 = gB2; gA3 = gB3;
                gB0 = gC0; gB1 = gC1; gB2 = gC2; gB3 = gC3;
            }
        }
        if (BIAS) {
            float4 b = ((const float4*)bias)[f];
            acc.x += b.x; acc.y += b.y; acc.z += b.z; acc.w += b.w;
        }
        if (RELU) {
            acc.x = fmaxf(acc.x, 0.f); acc.y = fmaxf(acc.y, 0.f);
            acc.z = fmaxf(acc.z, 0.f); acc.w = fmaxf(acc.w, 0.f);
        }
        if (!FINAL) {
            if (OBF) {
                uint2 o = {pk2(acc.x, acc.y), pk2(acc.z, acc.w)};
                ((uint2*)outv)[(size_t)node * 4 + f] = o;
            } else {
                ((float4*)outv)[(size_t)node * 4 + f] = acc;
            }
        }
    }
    if (GRAM) {
        __shared__ float Us[64 * 20];
        int nl = threadIdx.x >> 2;
        float4 z = valid ? acc : (float4){0, 0, 0, 0};
        ((float4*)&Us[nl * 20])[f] = z;
        __syncthreads();
        int k = threadIdx.x & 15, kp = threadIdx.x >> 4;
        float g = 0.f, s = 0.f;
        for (int n = 0; n < 64; n++) {
            float a = Us[n * 20 + k];
            float b = Us[n * 20 + kp];
            g = fmaf(a, b, g);
            s += a;
        }
        float* gs = GS + (blockIdx.x & 7) * 272;   // 8 copies -> 8x less contention
        atomicAdd(&gs[kp * 16 + k], g);
        if (kp == 0) atomicAdd(&gs[256 + k], s);
        // ---- fused bn_prep: last-block-done finalize ----
        __shared__ int isLast;
        __threadfence();
        __syncthreads();
        if (threadIdx.x == 0) {
            int prev = atomicAdd((int*)(GS + 8 * 272), 1);
            isLast = (prev == (int)gridDim.x - 1);
        }
        __syncthreads();
        if (isLast) {
            __shared__ float Gs[272];
            __threadfence();
            for (int i = threadIdx.x; i < 272; i += 256) {
                float a = 0.f;
                #pragma unroll
                for (int c = 0; c < 8; c++) a += atomicAdd(&GS[c * 272 + i], 0.f);
                Gs[i] = a;
            }
            __syncthreads();
            if (threadIdx.x < 128) {
                int d = threadIdx.x;
                float w[16];
                #pragma unroll
                for (int kk = 0; kk < 16; kk++) w[kk] = W2l[kk * DD + d];
                float sdot = 0.f, quad = 0.f;
                #pragma unroll
                for (int kk = 0; kk < 16; kk++) {
                    sdot = fmaf(Gs[256 + kk], w[kk], sdot);
                    float vk = 0.f;
                    #pragma unroll
                    for (int kq = 0; kq < 16; kq++) vk = fmaf(Gs[kk * 16 + kq], w[kq], vk);
                    quad = fmaf(w[kk], vk, quad);
                }
                float b = b2l[d];
                float sumH  = sdot + (float)NN * b;
                float sumsq = quad + 2.f * b * sdot + (float)NN * b * b;
                float mean = sumH * (1.f / NN);
                float var  = sumsq * (1.f / NN) - mean * mean;
                float inv  = rsqrtf(var + 1e-5f);
                float gm = gml[d] * inv;
                SCSH[d] = gm;
                SCSH[128 + d] = (b - mean) * gm + btl[d];
            }
        }
    }
    if (FINAL) {
        // classifier: out = acc(16) @ Wf(16x40) + bf, via LDS node-major buffer
        __shared__ float Us[64 * 20];
        int nl = threadIdx.x >> 2;
        ((float4*)&Us[nl * 20])[f] = acc;
        __syncthreads();
        int p = threadIdx.x & 3;
        if (valid) {
            float u[16];
            #pragma unroll
            for (int k = 0; k < 16; k++) u[k] = Us[(threadIdx.x >> 2) * 20 + k];
            float2 a5[5];
            #pragma unroll
            for (int i = 0; i < 5; i++) a5[i] = Bc[p * 5 + i];
            #pragma unroll
            for (int k = 0; k < 16; k++) {
                float uk = u[k];
                #pragma unroll
                for (int i = 0; i < 5; i++) {
                    float2 w = Wc[k * 20 + p * 5 + i];
                    a5[i].x = fmaf(uk, w.x, a5[i].x);
                    a5[i].y = fmaf(uk, w.y, a5[i].y);
                }
            }
            float2* O = (float2*)(outc + (size_t)node * CC) + p * 5;
            #pragma unroll
            for (int i = 0; i < 5; i++) O[i] = a5[i];
        }
    }
}

// ---- Y(bf16) = relu(BN(U@W2)) @ W1n ; 8 lanes/node x 2 nodes/thread,
//      64 nodes/block (1563 blocks), BN coeffs precomputed ----
__launch_bounds__(256)
__global__ void fused_mid(const float* __restrict__ U, const float* __restrict__ SCSH,
                          const float* __restrict__ W2, const float* __restrict__ W1n,
                          unsigned* __restrict__ Y) {
    __shared__ float4 W2s[HH * 32];      // (k,dw) at k*32 + permW2(dw)
    __shared__ float4 W1s[DD * 4];       // (d,q)  at d*4 + ((q + (d>>4)) & 3)
    __shared__ float4 SC4[32], SH4[32];  // permW2 layout
    int t = threadIdx.x;
    for (int i = t; i < HH * 32; i += 256) {
        int k = i >> 5, dw = i & 31;
        W2s[k * 32 + permW2(dw)] = ((const float4*)W2)[i];
    }
    for (int i = t; i < DD * 4; i += 256) {
        int d = i >> 2, q = i & 3;
        W1s[d * 4 + ((q + (d >> 4)) & 3)] = ((const float4*)W1n)[i];
    }
    if (t < 32) SC4[permW2(t)] = ((const float4*)SCSH)[t];
    else if (t < 64) SH4[permW2(t - 32)] = ((const float4*)SCSH)[t];
    __syncthreads();
    int g = t >> 3, p = t & 7;
    int base = blockIdx.x * 64;
    int n[2]; bool v[2];
    #pragma unroll
    for (int i = 0; i < 2; i++) { n[i] = base + i * 32 + g; v[i] = n[i] < NN; }
    float u[2][16];
    #pragma unroll
    for (int i = 0; i < 2; i++) {
        if (v[i]) {
            const float4* up = (const float4*)(U + (size_t)n[i] * HH);
            float4 a = up[0], b = up[1], c = up[2], d = up[3];
            u[i][0]=a.x; u[i][1]=a.y; u[i][2]=a.z; u[i][3]=a.w;
            u[i][4]=b.x; u[i][5]=b.y; u[i][6]=b.z; u[i][7]=b.w;
            u[i][8]=c.x; u[i][9]=c.y; u[i][10]=c.z; u[i][11]=c.w;
            u[i][12]=d.x; u[i][13]=d.y; u[i][14]=d.z; u[i][15]=d.w;
        } else {
            #pragma unroll
            for (int k = 0; k < 16; k++) u[i][k] = 0.f;
        }
    }
    float4 y[2][4];
    #pragma unroll
    for (int i = 0; i < 2; i++)
        #pragma unroll
        for (int q = 0; q < 4; q++) y[i][q] = {0, 0, 0, 0};
    #pragma unroll
    for (int dqi = 0; dqi < 4; dqi++) {
        int rpos = p + (dqi << 3);        // permW2(p*4+dqi)
        float4 h[2] = {{0,0,0,0},{0,0,0,0}};
        #pragma unroll
        for (int k = 0; k < 16; k++) {
            float4 w = W2s[k * 32 + rpos];
            h[0] = f4fma(u[0][k], w, h[0]);
            h[1] = f4fma(u[1][k], w, h[1]);
        }
        float4 s4 = SC4[rpos], t4 = SH4[rpos];
        #pragma unroll
        for (int i = 0; i < 2; i++) {
            h[i].x = fmaxf(fmaf(h[i].x, s4.x, t4.x), 0.f);
            h[i].y = fmaxf(fmaf(h[i].y, s4.y, t4.y), 0.f);
            h[i].z = fmaxf(fmaf(h[i].z, s4.z, t4.z), 0.f);
            h[i].w = fmaxf(fmaf(h[i].w, s4.w, t4.w), 0.f);
        }
        int dq = (p << 2) + dqi;
        #pragma unroll
        for (int j = 0; j < 4; j++) {
            int d = (dq << 2) + j;
            float4 w0 = W1s[d * 4 + ((0 + p) & 3)];
            float4 w1 = W1s[d * 4 + ((1 + p) & 3)];
            float4 w2 = W1s[d * 4 + ((2 + p) & 3)];
            float4 w3 = W1s[d * 4 + ((3 + p) & 3)];
            float h0 = j == 0 ? h[0].x : j == 1 ? h[0].y : j == 2 ? h[0].z : h[0].w;
            float h1 = j == 0 ? h[1].x : j == 1 ? h[1].y : j == 2 ? h[1].z : h[1].w;
            y[0][0] = f4fma(h0, w0, y[0][0]); y[0][1] = f4fma(h0, w1, y[0][1]);
            y[0][2] = f4fma(h0, w2, y[0][2]); y[0][3] = f4fma(h0, w3, y[0][3]);
            y[1][0] = f4fma(h1, w0, y[1][0]); y[1][1] = f4fma(h1, w1, y[1][1]);
            y[1][2] = f4fma(h1, w2, y[1][2]); y[1][3] = f4fma(h1, w3, y[1][3]);
        }
    }
    // merged transpose-reduce: xor-4 picks node, xor-2 picks quarter pair,
    // xor-1 picks quarter. All array indices static -> stays in VGPRs.
    float4 ar[4];
    #pragma unroll
    for (int q = 0; q < 4; q++) {
        float4 z0 = y[0][q], z1 = y[1][q];
        z0.x += __shfl_xor(z0.x, 4); z0.y += __shfl_xor(z0.y, 4);
        z0.z += __shfl_xor(z0.z, 4); z0.w += __shfl_xor(z0.w, 4);
        z1.x += __shfl_xor(z1.x, 4); z1.y += __shfl_xor(z1.y, 4);
        z1.z += __shfl_xor(z1.z, 4); z1.w += __shfl_xor(z1.w, 4);
        ar[q].x = (p & 4) ? z1.x : z0.x;
        ar[q].y = (p & 4) ? z1.y : z0.y;
        ar[q].z = (p & 4) ? z1.z : z0.z;
        ar[q].w = (p & 4) ? z1.w : z0.w;
    }
    float4 br[2];
    #pragma unroll
    for (int q = 0; q < 2; q++) {
        float4 z0 = ar[q], z1 = ar[2 + q];
        z0.x += __shfl_xor(z0.x, 2); z0.y += __shfl_xor(z0.y, 2);
        z0.z += __shfl_xor(z0.z, 2); z0.w += __shfl_xor(z0.w, 2);
        z1.x += __shfl_xor(z1.x, 2); z1.y += __shfl_xor(z1.y, 2);
        z1.z += __shfl_xor(z1.z, 2); z1.w += __shfl_xor(z1.w, 2);
        br[q].x = (p & 2) ? z1.x : z0.x;
        br[q].y = (p & 2) ? z1.y : z0.y;
        br[q].z = (p & 2) ? z1.z : z0.z;
        br[q].w = (p & 2) ? z1.w : z0.w;
    }
    float4 c;
    {
        float4 z0 = br[0], z1 = br[1];
        z0.x += __shfl_xor(z0.x, 1); z0.y += __shfl_xor(z0.y, 1);
        z0.z += __shfl_xor(z0.z, 1); z0.w += __shfl_xor(z0.w, 1);
        z1.x += __shfl_xor(z1.x, 1); z1.y += __shfl_xor(z1.y, 1);
        z1.z += __shfl_xor(z1.z, 1); z1.w += __shfl_xor(z1.w, 1);
        c.x = (p & 1) ? z1.x : z0.x;
        c.y = (p & 1) ? z1.y : z0.y;
        c.z = (p & 1) ? z1.z : z0.z;
        c.w = (p & 1) ? z1.w : z0.w;
    }
    bool vv = (p & 4) ? v[1] : v[0];
    int  nn = (p & 4) ? n[1] : n[0];
    int  q  = p & 3;
    if (vv) {
        uint2 o = {pk2(c.x, c.y), pk2(c.z, c.w)};
        ((uint2*)Y)[(size_t)nn * 4 + q] = o;
    }
}

extern "C" void kernel_launch(void* const* d_in, const int* in_sizes, int n_in,
                              void* d_out, int out_size, void* d_ws, size_t ws_size,
                              hipStream_t stream) {
    const float* x     = (const float*)d_in[0];
    const float* vals  = (const float*)d_in[1];
    const float* W1    = (const float*)d_in[2];
    const float* b1    = (const float*)d_in[3];
    const float* W2    = (const float*)d_in[4];
    const float* b2    = (const float*)d_in[5];
    const float* gamma = (const float*)d_in[6];
    const float* beta  = (const float*)d_in[7];
    const float* W1f   = (const float*)d_in[8];
    const float* b1f   = (const float*)d_in[9];
    const float* W2f   = (const float*)d_in[10];
    const float* b2f   = (const float*)d_in[11];
    const int*   row   = (const int*)d_in[12];
    const int*   col   = (const int*)d_in[13];
    float* out = (float*)d_out;

    char* ws = (char*)d_ws;
    size_t off = 0;
    auto alloc = [&](size_t bytes) -> char* {
        char* p = ws + off;
        off += (bytes + 255) / 256 * 256;
        return p;
    };
    int*      rp   = (int*)     alloc((NN + 1) * sizeof(int));
    float*    GSC  = (float*)   alloc((size_t)LL * GSTRIDE * sizeof(float));
    float*    SCSH = (float*)   alloc(256 * sizeof(float));
    unsigned* Yb   = (unsigned*)alloc((size_t)NN * HH * 2);   // bf16
    unsigned* Tb   = (unsigned*)alloc((size_t)NN * HH * 2);   // bf16
    float*    U    = (float*)   alloc((size_t)NN * HH * sizeof(float));

    build_rowptr<<<(NE + 255) / 256, 256, 0, stream>>>(row, rp);
    zero_buf<<<(LL * GSTRIDE + 255) / 256, 256, 0, stream>>>(GSC, LL * GSTRIDE);

    gemm_dh_reg<<<(NN + 255) / 256, 256, 0, stream>>>(x, W1, Yb);
    for (int l = 0; l < LL; l++) {
        spmm16<true, true, true, false, false><<<(NN + 63) / 64, 256, 0, stream>>>(
            rp, col, vals, Yb, b1 + l * HH, Tb, nullptr, nullptr, nullptr, nullptr,
            nullptr, nullptr, nullptr, nullptr, nullptr);
        spmm16<false, false, false, true, false><<<(NN + 63) / 64, 256, 0, stream>>>(
            rp, col, vals, Tb, nullptr, U, GSC + (size_t)l * GSTRIDE, nullptr, nullptr,
            nullptr, W2 + l * HH * DD, b2 + l * DD, gamma + l * DD, beta + l * DD, SCSH);
        const float* W1next = (l < LL - 1) ? (W1 + (l + 1) * DD * HH) : W1f;
        fused_mid<<<(NN + 63) / 64, 256, 0, stream>>>(U, SCSH, W2 + l * HH * DD, W1next, Yb);
    }
    spmm16<true, true, true, false, false><<<(NN + 63) / 64, 256, 0, stream>>>(
        rp, col, vals, Yb, b1f, Tb, nullptr, nullptr, nullptr, nullptr,
        nullptr, nullptr, nullptr, nullptr, nullptr);
    spmm16<false, false, false, false, true><<<(NN + 63) / 64, 256, 0, stream>>>(
        rp, col, vals, Tb, nullptr, nullptr, nullptr, W2f, b2f, out,
        nullptr, nullptr, nullptr, nullptr, nullptr);
}

// Round 9
// 368.134 us; speedup vs baseline: 2.0493x; 2.0493x over previous
//
#include <hip/hip_runtime.h>

#define NN 100000
#define NE 1600000
#define DD 128
#define HH 16
#define CC 40
#define LL 3

typedef int   vi4 __attribute__((ext_vector_type(4)));
typedef float vf4 __attribute__((ext_vector_type(4)));

__device__ __forceinline__ float4 f4fma(float s, float4 w, float4 a) {
    a.x = fmaf(s, w.x, a.x); a.y = fmaf(s, w.y, a.y);
    a.z = fmaf(s, w.z, a.z); a.w = fmaf(s, w.w, a.w);
    return a;
}

// bf16 helpers (RNE pack, shift unpack)
__device__ __forceinline__ unsigned short f2bf(float f) {
    unsigned u = __float_as_uint(f);
    unsigned r = u + 0x7fffu + ((u >> 16) & 1u);
    return (unsigned short)(r >> 16);
}
__device__ __forceinline__ unsigned pk2(float a, float b) {
    return (unsigned)f2bf(a) | ((unsigned)f2bf(b) << 16);
}
__device__ __forceinline__ float bflo(unsigned u) { return __uint_as_float(u << 16); }
__device__ __forceinline__ float bfhi(unsigned u) { return __uint_as_float(u & 0xffff0000u); }

// perm for [*][32]-float4 LDS arrays read at dw = p*4+dqi by 8 lanes p=0..7
__device__ __forceinline__ int permW2(int dw) {
    return (dw >> 2) | ((dw & 3) << 3);
}

// Edge-centric rowptr: rp[i] = first edge e with row[e] >= i (row sorted).
__global__ void build_rowptr(const int* __restrict__ row, int* __restrict__ rp) {
    int e = blockIdx.x * 256 + threadIdx.x;
    if (e >= NE) return;
    int r1 = row[e];
    int r0 = (e == 0) ? -1 : row[e - 1];
    for (int i = r0 + 1; i <= r1; i++) rp[i] = e;
    if (e == NE - 1) {
        for (int i = r1 + 1; i <= NN; i++) rp[i] = NE;
    }
}

__global__ void zero_buf(float* __restrict__ s, int n) {
    int i = blockIdx.x * 256 + threadIdx.x;
    if (i < n) s[i] = 0.f;
}

// ---- Y(bf16) = X @ W  (N x 128)@(128 x 16); thread-per-node ----
__launch_bounds__(256)
__global__ void gemm_dh_reg(const float* __restrict__ X, const float* __restrict__ W,
                            unsigned* __restrict__ Y) {
    __shared__ float4 Ws[DD * 4];
    int t = threadIdx.x;
    for (int i = t; i < DD * 4; i += 256) Ws[i] = ((const float4*)W)[i];
    __syncthreads();
    int n = blockIdx.x * 256 + t;
    if (n >= NN) return;
    const float4* X4 = (const float4*)(X + (size_t)n * DD);
    float4 y0 = {0,0,0,0}, y1 = {0,0,0,0}, y2 = {0,0,0,0}, y3 = {0,0,0,0};
    #pragma unroll 8
    for (int dc = 0; dc < 32; dc++) {
        float4 xv = X4[dc];
        float xs[4] = {xv.x, xv.y, xv.z, xv.w};
        #pragma unroll
        for (int j = 0; j < 4; j++) {
            int d = dc * 4 + j;
            float xj = xs[j];
            y0 = f4fma(xj, Ws[d * 4 + 0], y0);
            y1 = f4fma(xj, Ws[d * 4 + 1], y1);
            y2 = f4fma(xj, Ws[d * 4 + 2], y2);
            y3 = f4fma(xj, Ws[d * 4 + 3], y3);
        }
    }
    uint4 o0 = {pk2(y0.x, y0.y), pk2(y0.z, y0.w), pk2(y1.x, y1.y), pk2(y1.z, y1.w)};
    uint4 o1 = {pk2(y2.x, y2.y), pk2(y2.z, y2.w), pk2(y3.x, y3.y), pk2(y3.z, y3.w)};
    ((uint4*)Y)[(size_t)n * 2]     = o0;
    ((uint4*)Y)[(size_t)n * 2 + 1] = o1;
}

#define FMA_B(vv, g0, g1, g2, g3)                                                      \
    acc.x = fmaf(vv.x, bflo(g0.x), acc.x); acc.y = fmaf(vv.x, bfhi(g0.x), acc.y);      \
    acc.z = fmaf(vv.x, bflo(g0.y), acc.z); acc.w = fmaf(vv.x, bfhi(g0.y), acc.w);      \
    acc.x = fmaf(vv.y, bflo(g1.x), acc.x); acc.y = fmaf(vv.y, bfhi(g1.x), acc.y);      \
    acc.z = fmaf(vv.y, bflo(g1.y), acc.z); acc.w = fmaf(vv.y, bfhi(g1.y), acc.w);      \
    acc.x = fmaf(vv.z, bflo(g2.x), acc.x); acc.y = fmaf(vv.z, bfhi(g2.x), acc.y);      \
    acc.z = fmaf(vv.z, bflo(g2.y), acc.z); acc.w = fmaf(vv.z, bfhi(g2.y), acc.w);      \
    acc.x = fmaf(vv.w, bflo(g3.x), acc.x); acc.y = fmaf(vv.w, bfhi(g3.x), acc.y);      \
    acc.z = fmaf(vv.w, bflo(g3.y), acc.z); acc.w = fmaf(vv.w, bfhi(g3.y), acc.w);

// Aligned 4-edge batch load with range-zeroing: batch starts at jb (16B aligned,
// jb may dip below s and beyond e-1); out-of-range lanes get v=0 so the FMA is a
// no-op while col stays a valid gather address. NE % 4 == 0 keeps the last
// aligned vector load in-bounds. Plain loads: NT hints cost ~50-60us (R4/R6).
__device__ __forceinline__ void ldc(const int* __restrict__ col,
                                    const float* __restrict__ vals,
                                    int jb, int s, int e, vi4& c, vf4& v) {
    c = *(const vi4*)(col + jb);
    vf4 w = *(const vf4*)(vals + jb);
    int r = jb - s;
    unsigned deg = (unsigned)(e - s);
    v.x = ((unsigned)(r + 0) < deg) ? w.x : 0.f;
    v.y = ((unsigned)(r + 1) < deg) ? w.y : 0.f;
    v.z = ((unsigned)(r + 2) < deg) ? w.z : 0.f;
    v.w = ((unsigned)(r + 3) < deg) ? w.w : 0.f;
}

// ---- spmm over bf16 table; 4 lanes/node; optional fused Gram / classifier ----
// R2 structure exactly (best measured): uniform 3-stage pipeline
// (load b+3 | gather b+2 | FMA b), natural node order, stale tails,
// plain loads. No fences anywhere (R8: per-block __threadfence = 5x slowdown).
template <bool RELU, bool BIAS, bool OBF, bool GRAM, bool FINAL>
__launch_bounds__(256)
__global__ void spmm16(const int* __restrict__ rp, const int* __restrict__ col,
                       const float* __restrict__ vals, const unsigned* __restrict__ hin,
                       const float* __restrict__ bias, void* __restrict__ outv,
                       float* __restrict__ GS, const float* __restrict__ Wf,
                       const float* __restrict__ bf, float* __restrict__ outc) {
    __shared__ float2 Wc[FINAL ? HH * 20 : 1];
    __shared__ float2 Bc[FINAL ? 20 : 1];
    if (FINAL) {
        for (int i = threadIdx.x; i < HH * 20; i += 256) Wc[i] = ((const float2*)Wf)[i];
        if (threadIdx.x < 20) Bc[threadIdx.x] = ((const float2*)bf)[threadIdx.x];
    }
    int node = blockIdx.x * 64 + (threadIdx.x >> 2);
    int f = threadIdx.x & 3;
    bool valid = node < NN;
    if (!GRAM && !FINAL && !valid) return;
    float4 acc = {0, 0, 0, 0};
    if (valid) {
        int s = rp[node], e = rp[node + 1];
        const uint2* h2 = (const uint2*)hin;
        int deg = e - s;
        if (deg > 0) {
            int s0 = s & ~3;
            int B = (e - s0 + 3) >> 2;
            vi4 c2, c0, c1; vf4 v0, v1, v2;
            ldc(col, vals, s0, s, e, c0, v0);
            if (B > 1) ldc(col, vals, s0 + 4, s, e, c1, v1);
            else { c1 = c0; v1 = (vf4){0, 0, 0, 0}; }
            if (B > 2) ldc(col, vals, s0 + 8, s, e, c2, v2);
            else { c2 = c1; v2 = (vf4){0, 0, 0, 0}; }
            uint2 gA0 = h2[(size_t)c0.x * 4 + f], gA1 = h2[(size_t)c0.y * 4 + f];
            uint2 gA2 = h2[(size_t)c0.z * 4 + f], gA3 = h2[(size_t)c0.w * 4 + f];
            uint2 gB0 = h2[(size_t)c1.x * 4 + f], gB1 = h2[(size_t)c1.y * 4 + f];
            uint2 gB2 = h2[(size_t)c1.z * 4 + f], gB3 = h2[(size_t)c1.w * 4 + f];
            for (int b = 0; b < B; b++) {
                vi4 c3; vf4 v3;
                if (b + 3 < B) ldc(col, vals, s0 + ((b + 3) << 2), s, e, c3, v3);
                else { c3 = c2; v3 = (vf4){0, 0, 0, 0}; }
                uint2 gC0 = h2[(size_t)c2.x * 4 + f], gC1 = h2[(size_t)c2.y * 4 + f];
                uint2 gC2 = h2[(size_t)c2.z * 4 + f], gC3 = h2[(size_t)c2.w * 4 + f];
                FMA_B(v0, gA0, gA1, gA2, gA3)
                v0 = v1; v1 = v2; v2 = v3; c2 = c3;
                gA0 = gB0; gA1 = gB1; gA2 = gB2; gA3 = gB3;
                gB0 = gC0; gB1 = gC1; gB2 = gC2; gB3 = gC3;
            }
        }
        if (BIAS) {
            float4 b = ((const float4*)bias)[f];
            acc.x += b.x; acc.y += b.y; acc.z += b.z; acc.w += b.w;
        }
        if (RELU) {
            acc.x = fmaxf(acc.x, 0.f); acc.y = fmaxf(acc.y, 0.f);
            acc.z = fmaxf(acc.z, 0.f); acc.w = fmaxf(acc.w, 0.f);
        }
        if (!FINAL) {
            if (OBF) {
                uint2 o = {pk2(acc.x, acc.y), pk2(acc.z, acc.w)};
                ((uint2*)outv)[(size_t)node * 4 + f] = o;
            } else {
                ((float4*)outv)[(size_t)node * 4 + f] = acc;
            }
        }
    }
    if (GRAM) {
        __shared__ float Us[64 * 20];
        int nl = threadIdx.x >> 2;
        float4 z = valid ? acc : (float4){0, 0, 0, 0};
        ((float4*)&Us[nl * 20])[f] = z;
        __syncthreads();
        int k = threadIdx.x & 15, kp = threadIdx.x >> 4;
        float g = 0.f, s = 0.f;
        for (int n = 0; n < 64; n++) {
            float a = Us[n * 20 + k];
            float b = Us[n * 20 + kp];
            g = fmaf(a, b, g);
            s += a;
        }
        float* gs = GS + (blockIdx.x & 7) * 272;   // 8 copies -> 8x less contention
        atomicAdd(&gs[kp * 16 + k], g);
        if (kp == 0) atomicAdd(&gs[256 + k], s);
    }
    if (FINAL) {
        // classifier: out = acc(16) @ Wf(16x40) + bf, via LDS node-major buffer
        __shared__ float Us[64 * 20];
        int nl = threadIdx.x >> 2;
        ((float4*)&Us[nl * 20])[f] = acc;
        __syncthreads();
        int p = threadIdx.x & 3;
        if (valid) {
            float u[16];
            #pragma unroll
            for (int k = 0; k < 16; k++) u[k] = Us[(threadIdx.x >> 2) * 20 + k];
            float2 a5[5];
            #pragma unroll
            for (int i = 0; i < 5; i++) a5[i] = Bc[p * 5 + i];
            #pragma unroll
            for (int k = 0; k < 16; k++) {
                float uk = u[k];
                #pragma unroll
                for (int i = 0; i < 5; i++) {
                    float2 w = Wc[k * 20 + p * 5 + i];
                    a5[i].x = fmaf(uk, w.x, a5[i].x);
                    a5[i].y = fmaf(uk, w.y, a5[i].y);
                }
            }
            float2* O = (float2*)(outc + (size_t)node * CC) + p * 5;
            #pragma unroll
            for (int i = 0; i < 5; i++) O[i] = a5[i];
        }
    }
}

// ---- Y(bf16) = relu(BN(U@W2)) @ W1n ; 8 lanes/node x 2 nodes/thread ----
// bn_prep is folded in as redundant per-block compute: each block sums the 8
// Gram copies (8.7 KB, L2-hit) and derives the BN scale/shift into LDS. GSC is
// complete at the launch boundary -- no fences, no inter-block sync. Same
// summation order as the old bn_prep kernel (bit-identical SCSH).
__launch_bounds__(256)
__global__ void fused_mid(const float* __restrict__ U, const float* __restrict__ GS,
                          const float* __restrict__ W2, const float* __restrict__ b2,
                          const float* __restrict__ gamma, const float* __restrict__ beta,
                          const float* __restrict__ W1n, unsigned* __restrict__ Y) {
    __shared__ float4 W2s[HH * 32];      // (k,dw) at k*32 + permW2(dw)
    __shared__ float4 W1s[DD * 4];       // (d,q)  at d*4 + ((q + (d>>4)) & 3)
    __shared__ float4 SC4[32], SH4[32];  // permW2 layout
    __shared__ float  Gs[272];
    int t = threadIdx.x;
    for (int i = t; i < HH * 32; i += 256) {
        int k = i >> 5, dw = i & 31;
        W2s[k * 32 + permW2(dw)] = ((const float4*)W2)[i];
    }
    for (int i = t; i < DD * 4; i += 256) {
        int d = i >> 2, q = i & 3;
        W1s[d * 4 + ((q + (d >> 4)) & 3)] = ((const float4*)W1n)[i];
    }
    for (int i = t; i < 272; i += 256) {
        float a = 0.f;
        #pragma unroll
        for (int c = 0; c < 8; c++) a += GS[c * 272 + i];
        Gs[i] = a;
    }
    __syncthreads();
    if (t < 128) {
        int d = t;
        float w[16];
        #pragma unroll
        for (int kk = 0; kk < 16; kk++) w[kk] = W2[kk * DD + d];
        float sdot = 0.f, quad = 0.f;
        #pragma unroll
        for (int kk = 0; kk < 16; kk++) {
            sdot = fmaf(Gs[256 + kk], w[kk], sdot);
            float vk = 0.f;
            #pragma unroll
            for (int kq = 0; kq < 16; kq++) vk = fmaf(Gs[kk * 16 + kq], w[kq], vk);
            quad = fmaf(w[kk], vk, quad);
        }
        float b = b2[d];
        float sumH  = sdot + (float)NN * b;
        float sumsq = quad + 2.f * b * sdot + (float)NN * b * b;
        float mean = sumH * (1.f / NN);
        float var  = sumsq * (1.f / NN) - mean * mean;
        float inv  = rsqrtf(var + 1e-5f);
        float gm = gamma[d] * inv;
        ((float*)&SC4[permW2(d >> 2)])[d & 3] = gm;
        ((float*)&SH4[permW2(d >> 2)])[d & 3] = (b - mean) * gm + beta[d];
    }
    __syncthreads();
    int g = t >> 3, p = t & 7;
    int base = blockIdx.x * 64;
    int n[2]; bool v[2];
    #pragma unroll
    for (int i = 0; i < 2; i++) { n[i] = base + i * 32 + g; v[i] = n[i] < NN; }
    float u[2][16];
    #pragma unroll
    for (int i = 0; i < 2; i++) {
        if (v[i]) {
            const float4* up = (const float4*)(U + (size_t)n[i] * HH);
            float4 a = up[0], b = up[1], c = up[2], d = up[3];
            u[i][0]=a.x; u[i][1]=a.y; u[i][2]=a.z; u[i][3]=a.w;
            u[i][4]=b.x; u[i][5]=b.y; u[i][6]=b.z; u[i][7]=b.w;
            u[i][8]=c.x; u[i][9]=c.y; u[i][10]=c.z; u[i][11]=c.w;
            u[i][12]=d.x; u[i][13]=d.y; u[i][14]=d.z; u[i][15]=d.w;
        } else {
            #pragma unroll
            for (int k = 0; k < 16; k++) u[i][k] = 0.f;
        }
    }
    float4 y[2][4];
    #pragma unroll
    for (int i = 0; i < 2; i++)
        #pragma unroll
        for (int q = 0; q < 4; q++) y[i][q] = {0, 0, 0, 0};
    #pragma unroll
    for (int dqi = 0; dqi < 4; dqi++) {
        int rpos = p + (dqi << 3);        // permW2(p*4+dqi)
        float4 h[2] = {{0,0,0,0},{0,0,0,0}};
        #pragma unroll
        for (int k = 0; k < 16; k++) {
            float4 w = W2s[k * 32 + rpos];
            h[0] = f4fma(u[0][k], w, h[0]);
            h[1] = f4fma(u[1][k], w, h[1]);
        }
        float4 s4 = SC4[rpos], t4 = SH4[rpos];
        #pragma unroll
        for (int i = 0; i < 2; i++) {
            h[i].x = fmaxf(fmaf(h[i].x, s4.x, t4.x), 0.f);
            h[i].y = fmaxf(fmaf(h[i].y, s4.y, t4.y), 0.f);
            h[i].z = fmaxf(fmaf(h[i].z, s4.z, t4.z), 0.f);
            h[i].w = fmaxf(fmaf(h[i].w, s4.w, t4.w), 0.f);
        }
        int dq = (p << 2) + dqi;
        #pragma unroll
        for (int j = 0; j < 4; j++) {
            int d = (dq << 2) + j;
            float4 w0 = W1s[d * 4 + ((0 + p) & 3)];
            float4 w1 = W1s[d * 4 + ((1 + p) & 3)];
            float4 w2 = W1s[d * 4 + ((2 + p) & 3)];
            float4 w3 = W1s[d * 4 + ((3 + p) & 3)];
            float h0 = j == 0 ? h[0].x : j == 1 ? h[0].y : j == 2 ? h[0].z : h[0].w;
            float h1 = j == 0 ? h[1].x : j == 1 ? h[1].y : j == 2 ? h[1].z : h[1].w;
            y[0][0] = f4fma(h0, w0, y[0][0]); y[0][1] = f4fma(h0, w1, y[0][1]);
            y[0][2] = f4fma(h0, w2, y[0][2]); y[0][3] = f4fma(h0, w3, y[0][3]);
            y[1][0] = f4fma(h1, w0, y[1][0]); y[1][1] = f4fma(h1, w1, y[1][1]);
            y[1][2] = f4fma(h1, w2, y[1][2]); y[1][3] = f4fma(h1, w3, y[1][3]);
        }
    }
    // merged transpose-reduce: xor-4 picks node, xor-2 picks quarter pair,
    // xor-1 picks quarter. All array indices static -> stays in VGPRs.
    float4 ar[4];
    #pragma unroll
    for (int q = 0; q < 4; q++) {
        float4 z0 = y[0][q], z1 = y[1][q];
        z0.x += __shfl_xor(z0.x, 4); z0.y += __shfl_xor(z0.y, 4);
        z0.z += __shfl_xor(z0.z, 4); z0.w += __shfl_xor(z0.w, 4);
        z1.x += __shfl_xor(z1.x, 4); z1.y += __shfl_xor(z1.y, 4);
        z1.z += __shfl_xor(z1.z, 4); z1.w += __shfl_xor(z1.w, 4);
        ar[q].x = (p & 4) ? z1.x : z0.x;
        ar[q].y = (p & 4) ? z1.y : z0.y;
        ar[q].z = (p & 4) ? z1.z : z0.z;
        ar[q].w = (p & 4) ? z1.w : z0.w;
    }
    float4 br[2];
    #pragma unroll
    for (int q = 0; q < 2; q++) {
        float4 z0 = ar[q], z1 = ar[2 + q];
        z0.x += __shfl_xor(z0.x, 2); z0.y += __shfl_xor(z0.y, 2);
        z0.z += __shfl_xor(z0.z, 2); z0.w += __shfl_xor(z0.w, 2);
        z1.x += __shfl_xor(z1.x, 2); z1.y += __shfl_xor(z1.y, 2);
        z1.z += __shfl_xor(z1.z, 2); z1.w += __shfl_xor(z1.w, 2);
        br[q].x = (p & 2) ? z1.x : z0.x;
        br[q].y = (p & 2) ? z1.y : z0.y;
        br[q].z = (p & 2) ? z1.z : z0.z;
        br[q].w = (p & 2) ? z1.w : z0.w;
    }
    float4 c;
    {
        float4 z0 = br[0], z1 = br[1];
        z0.x += __shfl_xor(z0.x, 1); z0.y += __shfl_xor(z0.y, 1);
        z0.z += __shfl_xor(z0.z, 1); z0.w += __shfl_xor(z0.w, 1);
        z1.x += __shfl_xor(z1.x, 1); z1.y += __shfl_xor(z1.y, 1);
        z1.z += __shfl_xor(z1.z, 1); z1.w += __shfl_xor(z1.w, 1);
        c.x = (p & 1) ? z1.x : z0.x;
        c.y = (p & 1) ? z1.y : z0.y;
        c.z = (p & 1) ? z1.z : z0.z;
        c.w = (p & 1) ? z1.w : z0.w;
    }
    bool vv = (p & 4) ? v[1] : v[0];
    int  nn = (p & 4) ? n[1] : n[0];
    int  q  = p & 3;
    if (vv) {
        uint2 o = {pk2(c.x, c.y), pk2(c.z, c.w)};
        ((uint2*)Y)[(size_t)nn * 4 + q] = o;
    }
}

extern "C" void kernel_launch(void* const* d_in, const int* in_sizes, int n_in,
                              void* d_out, int out_size, void* d_ws, size_t ws_size,
                              hipStream_t stream) {
    const float* x     = (const float*)d_in[0];
    const float* vals  = (const float*)d_in[1];
    const float* W1    = (const float*)d_in[2];
    const float* b1    = (const float*)d_in[3];
    const float* W2    = (const float*)d_in[4];
    const float* b2    = (const float*)d_in[5];
    const float* gamma = (const float*)d_in[6];
    const float* beta  = (const float*)d_in[7];
    const float* W1f   = (const float*)d_in[8];
    const float* b1f   = (const float*)d_in[9];
    const float* W2f   = (const float*)d_in[10];
    const float* b2f   = (const float*)d_in[11];
    const int*   row   = (const int*)d_in[12];
    const int*   col   = (const int*)d_in[13];
    float* out = (float*)d_out;

    char* ws = (char*)d_ws;
    size_t off = 0;
    auto alloc = [&](size_t bytes) -> char* {
        char* p = ws + off;
        off += (bytes + 255) / 256 * 256;
        return p;
    };
    int*      rp   = (int*)     alloc((NN + 1) * sizeof(int));
    float*    GSC  = (float*)   alloc((size_t)LL * 8 * 272 * sizeof(float));
    unsigned* Yb   = (unsigned*)alloc((size_t)NN * HH * 2);   // bf16
    unsigned* Tb   = (unsigned*)alloc((size_t)NN * HH * 2);   // bf16
    float*    U    = (float*)   alloc((size_t)NN * HH * sizeof(float));

    build_rowptr<<<(NE + 255) / 256, 256, 0, stream>>>(row, rp);
    zero_buf<<<(LL * 8 * 272 + 255) / 256, 256, 0, stream>>>(GSC, LL * 8 * 272);

    gemm_dh_reg<<<(NN + 255) / 256, 256, 0, stream>>>(x, W1, Yb);
    for (int l = 0; l < LL; l++) {
        spmm16<true, true, true, false, false><<<(NN + 63) / 64, 256, 0, stream>>>(
            rp, col, vals, Yb, b1 + l * HH, Tb, nullptr, nullptr, nullptr, nullptr);
        spmm16<false, false, false, true, false><<<(NN + 63) / 64, 256, 0, stream>>>(
            rp, col, vals, Tb, nullptr, U, GSC + (size_t)l * 8 * 272, nullptr, nullptr, nullptr);
        const float* W1next = (l < LL - 1) ? (W1 + (l + 1) * DD * HH) : W1f;
        fused_mid<<<(NN + 63) / 64, 256, 0, stream>>>(
            U, GSC + (size_t)l * 8 * 272, W2 + l * HH * DD, b2 + l * DD,
            gamma + l * DD, beta + l * DD, W1next, Yb);
    }
    spmm16<true, true, true, false, false><<<(NN + 63) / 64, 256, 0, stream>>>(
        rp, col, vals, Yb, b1f, Tb, nullptr, nullptr, nullptr, nullptr);
    spmm16<false, false, false, false, true><<<(NN + 63) / 64, 256, 0, stream>>>(
        rp, col, vals, Tb, nullptr, nullptr, nullptr, W2f, b2f, out);
}